// Round 1
// baseline (4770.975 us; speedup 1.0000x reference)
//
#include <hip/hip_runtime.h>
#include <cstdint>
#include <cstddef>

#define HWSZ 65536  // 256*256

__device__ __forceinline__ uint32_t f2bfu(float f) {
  union { float f; uint32_t u; } v; v.f = f;
  return (v.u + 0x7FFFu + ((v.u >> 16) & 1u)) >> 16;  // RNE bf16, as uint
}
__device__ __forceinline__ float bfu2f(uint32_t s) {
  union { uint32_t u; float f; } v; v.u = s << 16;
  return v.f;
}
__device__ __forceinline__ float bfhi(uint32_t u) {  // high bf16 of pair
  union { uint32_t u; float f; } v; v.u = u & 0xffff0000u;
  return v.f;
}
__device__ __forceinline__ float bflo(uint32_t u) {  // low bf16 of pair
  union { uint32_t u; float f; } v; v.u = u << 16;
  return v.f;
}

// ---------------- K0: spatial kernel from rfft2 filter --------------------
__global__ void k_prep(const float* __restrict__ F, float* __restrict__ Ks) {
  __shared__ float ct[8];
  int t = threadIdx.x;
  int c = blockIdx.x;
  if (t == 0) {
    const float r2 = 0.70710678118654752f;
    ct[0] = 1.f; ct[1] = r2; ct[2] = 0.f; ct[3] = -r2;
    ct[4] = -1.f; ct[5] = -r2; ct[6] = 0.f; ct[7] = r2;
  }
  __syncthreads();
  int p = t >> 3, q = t & 7;
  const float* Fc = F + c * 40;
  float s = 0.f;
#pragma unroll
  for (int u = 0; u < 8; ++u) {
#pragma unroll
    for (int v = 0; v < 8; ++v) {
      float g = (v <= 4) ? Fc[u * 5 + v] : Fc[((8 - u) & 7) * 5 + (8 - v)];
      s += g * ct[(u * p + v * q) & 7];
    }
  }
  Ks[c * 64 + t] = s * (1.f / 64.f);
}

// ---------------- K0b: transpose w_out [64][256] -> wT [256][64] ----------
__global__ void k_wt(const float* __restrict__ w_out, float* __restrict__ wT) {
  int c = blockIdx.x;   // 256
  int d = threadIdx.x;  // 64
  wT[c * 64 + d] = w_out[d * 256 + c];
}

// ---------------- K1: conv_in 1x1 + bias + patch circular conv ------------
// one 8x8 patch per block, thread = channel c (0..255)
// v2: NO LDS staging for x or w. x-patch values are wave-uniform -> scalar
// loads (s_load) feeding v_fma SGPR operand; w row is per-lane from global
// (L1/L2-hot, 256B/thread). LDS = bf16 su staging only (34816 B).
// __launch_bounds__(256,3): 3 waves/SIMD (VGPR<=168), 3 blocks/CU.
// mid layout (uint32 = 2 bf16 pixels): [b][patch][c][pix/2] -> block-contig 32KB
__global__ __launch_bounds__(256, 3) void k_front(
    const float* __restrict__ x, const float* __restrict__ w_in,
    const float* __restrict__ b_in, const float* __restrict__ Ks,
    uint32_t* __restrict__ midu) {
  __shared__ uint32_t su[256 * 34];  // 34816 B bf16-pair staging
  int tid = threadIdx.x;
  int orig = blockIdx.x;
  int pid = (orig & 7) * 1024 + (orig >> 3);  // XCD swizzle (8192 % 8 == 0)
  int b = pid >> 10;
  int pp = pid & 1023;
  int ph = pp >> 5, pw = pp & 31;

  int c = tid;
  float bias = b_in[c];
  float p[64];
#pragma unroll
  for (int t = 0; t < 64; ++t) p[t] = bias;

  // conv_in: p[pix] = bias + sum_d w[c][d] * x[d][pix]
  // xb is block-uniform -> compiler emits s_load for xr[...] (scalar pipe);
  // wrow is per-lane (thread's own 64-float row, stride 256B -> L1/L2-hot).
  const float* xb = x + (size_t)b * 64 * HWSZ + (ph * 8) * 256 + pw * 8;
  const float* wrow = w_in + c * 64;
  for (int d8 = 0; d8 < 8; ++d8) {
    float4 wa = *(const float4*)(wrow + d8 * 8);
    float4 wb = *(const float4*)(wrow + d8 * 8 + 4);
    float wv[8] = {wa.x, wa.y, wa.z, wa.w, wb.x, wb.y, wb.z, wb.w};
#pragma unroll
    for (int dd = 0; dd < 8; ++dd) {
      const float* xr = xb + (size_t)(d8 * 8 + dd) * HWSZ;
#pragma unroll
      for (int i = 0; i < 8; ++i) {
#pragma unroll
        for (int j = 0; j < 8; ++j)
          p[i * 8 + j] += wv[dd] * xr[i * 256 + j];
      }
    }
  }

  // load per-channel spatial kernel AFTER conv_in (keeps peak VGPR low)
  float kreg[64];
  {
    const float4* kp = (const float4*)(Ks + c * 64);
#pragma unroll
    for (int t4 = 0; t4 < 16; ++t4) {
      float4 kv = kp[t4];
      kreg[t4 * 4 + 0] = kv.x; kreg[t4 * 4 + 1] = kv.y;
      kreg[t4 * 4 + 2] = kv.z; kreg[t4 * 4 + 3] = kv.w;
    }
  }

  // 8x8 circular conv, fully unrolled; pack bf16 pairs; stage in LDS
  uint32_t* srow = su + c * 34;
#pragma unroll
  for (int i = 0; i < 8; ++i) {
    float o[8] = {0.f, 0.f, 0.f, 0.f, 0.f, 0.f, 0.f, 0.f};
#pragma unroll
    for (int tp = 0; tp < 8; ++tp) {
      int r = ((i - tp) & 7) * 8;
#pragma unroll
      for (int tq = 0; tq < 8; ++tq) {
        float kv = kreg[tp * 8 + tq];
#pragma unroll
        for (int j = 0; j < 8; ++j) o[j] += kv * p[r + ((j - tq) & 7)];
      }
    }
    uint2 u0, u1;
    u0.x = f2bfu(o[0]) | (f2bfu(o[1]) << 16);
    u0.y = f2bfu(o[2]) | (f2bfu(o[3]) << 16);
    u1.x = f2bfu(o[4]) | (f2bfu(o[5]) << 16);
    u1.y = f2bfu(o[6]) | (f2bfu(o[7]) << 16);
    *(uint2*)(srow + i * 4) = u0;
    *(uint2*)(srow + i * 4 + 2) = u1;
  }
  __syncthreads();

  // cooperative fully-coalesced write: 8192 uints (32 KB) per block
  uint32_t* gbase = midu + (size_t)(b * 1024 + pp) * 8192;
#pragma unroll
  for (int k = 0; k < 8; ++k) {
    int g = tid * 4 + k * 1024;
    int cc = g >> 5, w = g & 31;
    uint2 a = *(uint2*)(su + cc * 34 + w);
    uint2 e = *(uint2*)(su + cc * 34 + w + 2);
    uint4 q; q.x = a.x; q.y = a.y; q.z = e.x; q.w = e.y;
    *(uint4*)(gbase + g) = q;
  }
}

// ---------------- K2 v3: dw7x7 + bias + GELU + conv_out 1x1 + bias --------
// Block = 32 wide x 16 tall px (1024 blocks). Thread = 2 adjacent px (2tx,
// 2tx+1) in row ty. Tile: bf16-pair uints [22 rows][TU=22], double-buffered.
// dw window read as 3x ds_read_b64/row; all weights via wave-uniform global
// loads (s_load path) -> zero LDS traffic for weights. acc[2][64] in VGPRs.
#define TU 22
__global__ __launch_bounds__(256, 1) void k_back(
    const uint32_t* __restrict__ midu, const float* __restrict__ w_dw,
    const float* __restrict__ b_dw, const float* __restrict__ wT,
    const float* __restrict__ b_out, float* __restrict__ out) {
  __shared__ uint32_t tile[2][22 * TU];  // 3872 B
  int t = threadIdx.x;
  int orig = blockIdx.x;
  int pid = (orig & 7) * 128 + (orig >> 3);  // XCD swizzle (1024 % 8 == 0)
  int b = pid >> 7;
  int tb = pid & 127;
  int th = tb >> 3, tw = tb & 7;  // 16 row-tiles x 8 col-tiles
  int R0 = th * 16, C0 = tw * 32;

  // zero-init both buffers; out-of-image slots stay zero for ALL channels
  for (int z = t; z < 2 * 22 * TU; z += 256) ((uint32_t*)tile)[z] = 0u;

  // loader: t<176: lr = t>>3 (row 0..21), pk = t&7 (patch col 0..5 active)
  int lr = t >> 3, pk = t & 7;
  int g = R0 - 3 + lr;            // global px row
  int pc = 4 * tw - 1 + pk;       // global patch col
  bool ldv = (t < 176) && (pk < 6) && ((unsigned)g < 256u) &&
             ((unsigned)pc < 32u);
  size_t src0 = 0;
  if (ldv)
    src0 = ((size_t)(b * 1024 + (g >> 3) * 32 + pc) * 8192) +
           (size_t)((g & 7) * 4);
  int u0 = 4 * pk - 2;  // lds uint col of quad start (pk=0 -> partial)

  int ty = t >> 4, tx = t & 15;
  int ue = tx & ~1;  // even-floor uint col for b64 window reads
  int o = tx & 1;

  float acc0[64], acc1[64];
#pragma unroll
  for (int d = 0; d < 64; ++d) { acc0[d] = 0.f; acc1[d] = 0.f; }

  __syncthreads();  // zero-init complete before prologue stores (R2 lesson)

  // prologue: stage channel 0 into buffer 0
  if (ldv) {
    uint4 q = *(const uint4*)(midu + src0);
    uint32_t* dr = &tile[0][0] + lr * TU;
    if (pk) {
      uint2 h0; h0.x = q.x; h0.y = q.y;
      uint2 h1; h1.x = q.z; h1.y = q.w;
      *(uint2*)(dr + u0) = h0;
      *(uint2*)(dr + u0 + 2) = h1;
    } else {
      uint2 h1; h1.x = q.z; h1.y = q.w;
      *(uint2*)(dr + 0) = h1;  // only px_rel -4..-1 half lands in-window
    }
  }
  __syncthreads();

  for (int c = 0; c < 256; ++c) {
    int cur = c & 1;
    uint4 q;
    bool pf = (c < 255) && ldv;
    if (pf) q = *(const uint4*)(midu + src0 + (size_t)(c + 1) * 32);

    const uint32_t* tl = &tile[cur][0];
    const float* wr = w_dw + c * 49;  // uniform -> s_load
    float s0 = b_dw[c], s1 = s0;
#pragma unroll
    for (int u = 0; u < 7; ++u) {
      const uint32_t* row = tl + (ty + u) * TU + ue;
      uint2 A = *(const uint2*)(row);
      uint2 B = *(const uint2*)(row + 2);
      uint2 C = *(const uint2*)(row + 4);
      uint32_t sw0 = o ? A.y : A.x;
      uint32_t sw1 = o ? B.x : A.y;
      uint32_t sw2 = o ? B.y : B.x;
      uint32_t sw3 = o ? C.x : B.y;
      uint32_t sw4 = o ? C.y : C.x;
      float f0 = bfhi(sw0), f1 = bflo(sw1), f2 = bfhi(sw1), f3 = bflo(sw2);
      float f4 = bfhi(sw2), f5 = bflo(sw3), f6 = bfhi(sw3), f7 = bflo(sw4);
      float w0 = wr[u * 7 + 0], w1 = wr[u * 7 + 1], w2 = wr[u * 7 + 2];
      float w3 = wr[u * 7 + 3], w4 = wr[u * 7 + 4], w5 = wr[u * 7 + 5];
      float w6 = wr[u * 7 + 6];
      s0 += w0 * f0 + w1 * f1 + w2 * f2 + w3 * f3 + w4 * f4 + w5 * f5 +
            w6 * f6;
      s1 += w0 * f1 + w1 * f2 + w2 * f3 + w3 * f4 + w4 * f5 + w5 * f6 +
            w6 * f7;
    }
    const float RS2 = 0.70710678118654752f;
    float g0 = 0.5f * s0 * (1.f + erff(s0 * RS2));
    float g1 = 0.5f * s1 * (1.f + erff(s1 * RS2));

    const float* wc = wT + c * 64;  // uniform -> s_load
#pragma unroll
    for (int d4 = 0; d4 < 16; ++d4) {
      float4 wv = *(const float4*)(wc + d4 * 4);
      acc0[d4 * 4 + 0] += g0 * wv.x; acc1[d4 * 4 + 0] += g1 * wv.x;
      acc0[d4 * 4 + 1] += g0 * wv.y; acc1[d4 * 4 + 1] += g1 * wv.y;
      acc0[d4 * 4 + 2] += g0 * wv.z; acc1[d4 * 4 + 2] += g1 * wv.z;
      acc0[d4 * 4 + 3] += g0 * wv.w; acc1[d4 * 4 + 3] += g1 * wv.w;
    }

    if (pf) {
      uint32_t* dr = &tile[cur ^ 1][0] + lr * TU;
      if (pk) {
        uint2 h0; h0.x = q.x; h0.y = q.y;
        uint2 h1; h1.x = q.z; h1.y = q.w;
        *(uint2*)(dr + u0) = h0;
        *(uint2*)(dr + u0 + 2) = h1;
      } else {
        uint2 h1; h1.x = q.z; h1.y = q.w;
        *(uint2*)(dr + 0) = h1;
      }
    }
    __syncthreads();
  }

  // coalesced float2 stores: lanes cover consecutive 8B spans of each row
  size_t obase = (size_t)b * 64 * HWSZ + (size_t)(R0 + ty) * 256 + C0 + 2 * tx;
#pragma unroll
  for (int d = 0; d < 64; ++d) {
    float bo = b_out[d];  // uniform -> s_load
    float2 v; v.x = acc0[d] + bo; v.y = acc1[d] + bo;
    *(float2*)(out + obase + (size_t)d * HWSZ) = v;
  }
}

extern "C" void kernel_launch(void* const* d_in, const int* in_sizes, int n_in,
                              void* d_out, int out_size, void* d_ws, size_t ws_size,
                              hipStream_t stream) {
  (void)in_sizes; (void)n_in; (void)out_size; (void)ws_size;
  const float* x     = (const float*)d_in[0];
  const float* w_in  = (const float*)d_in[1];
  const float* b_in  = (const float*)d_in[2];
  const float* fftf  = (const float*)d_in[3];
  const float* w_dw  = (const float*)d_in[4];
  const float* b_dw  = (const float*)d_in[5];
  const float* w_out = (const float*)d_in[6];
  const float* b_out = (const float*)d_in[7];
  float* out = (float*)d_out;

  float* Ks = (float*)d_ws;                                   // 64 KB
  float* wT = (float*)((char*)d_ws + 65536);                  // 64 KB
  uint32_t* midu = (uint32_t*)((char*)d_ws + 131072);         // 268 MB

  k_prep<<<256, 64, 0, stream>>>(fftf, Ks);
  k_wt<<<256, 64, 0, stream>>>(w_out, wT);
  k_front<<<8192, 256, 0, stream>>>(x, w_in, b_in, Ks, midu);
  k_back<<<1024, 256, 0, stream>>>(midu, w_dw, b_dw, wT, b_out, out);
}

// Round 2
// 3334.437 us; speedup vs baseline: 1.4308x; 1.4308x over previous
//
#include <hip/hip_runtime.h>
#include <cstdint>
#include <cstddef>

#define HWSZ 65536  // 256*256

__device__ __forceinline__ uint32_t f2bfu(float f) {
  union { float f; uint32_t u; } v; v.f = f;
  return (v.u + 0x7FFFu + ((v.u >> 16) & 1u)) >> 16;  // RNE bf16, as uint
}
__device__ __forceinline__ float bfu2f(uint32_t s) {
  union { uint32_t u; float f; } v; v.u = s << 16;
  return v.f;
}
__device__ __forceinline__ float bfhi(uint32_t u) {  // high bf16 of pair
  union { uint32_t u; float f; } v; v.u = u & 0xffff0000u;
  return v.f;
}
__device__ __forceinline__ float bflo(uint32_t u) {  // low bf16 of pair
  union { uint32_t u; float f; } v; v.u = u << 16;
  return v.f;
}

// ---------------- K0: spatial kernel from rfft2 filter --------------------
__global__ void k_prep(const float* __restrict__ F, float* __restrict__ Ks) {
  __shared__ float ct[8];
  int t = threadIdx.x;
  int c = blockIdx.x;
  if (t == 0) {
    const float r2 = 0.70710678118654752f;
    ct[0] = 1.f; ct[1] = r2; ct[2] = 0.f; ct[3] = -r2;
    ct[4] = -1.f; ct[5] = -r2; ct[6] = 0.f; ct[7] = r2;
  }
  __syncthreads();
  int p = t >> 3, q = t & 7;
  const float* Fc = F + c * 40;
  float s = 0.f;
#pragma unroll
  for (int u = 0; u < 8; ++u) {
#pragma unroll
    for (int v = 0; v < 8; ++v) {
      float g = (v <= 4) ? Fc[u * 5 + v] : Fc[((8 - u) & 7) * 5 + (8 - v)];
      s += g * ct[(u * p + v * q) & 7];
    }
  }
  Ks[c * 64 + t] = s * (1.f / 64.f);
}

// ---------------- K0b: transpose w_out [64][256] -> wT [256][64] ----------
__global__ void k_wt(const float* __restrict__ w_out, float* __restrict__ wT) {
  int c = blockIdx.x;   // 256
  int d = threadIdx.x;  // 64
  wT[c * 64 + d] = w_out[d * 256 + c];
}

// ---------------- K1: conv_in 1x1 + bias + patch circular conv ------------
// one 8x8 patch per block, thread = channel c (0..255)
// v3: x staged in LDS (16 KB, proven no-spill path); w_in read per-lane from
// global in 8-float chunks (L2-hot, kills the 64 KB wl buffer). LDS total
// 51200 B -> 3 blocks/CU under __launch_bounds__(256,3) (VGPR cap 168;
// circ-conv peak demand ~146: p[64]+kreg[64]+o[8]).
// mid layout (uint32 = 2 bf16 pixels): [b][patch][c][pix/2] -> block-contig 32KB
__global__ __launch_bounds__(256, 3) void k_front(
    const float* __restrict__ x, const float* __restrict__ w_in,
    const float* __restrict__ b_in, const float* __restrict__ Ks,
    uint32_t* __restrict__ midu) {
  __shared__ float xs[64 * 64];      // 16 KB [d][pix]
  __shared__ uint32_t su[256 * 34];  // 34816 B bf16-pair staging
  int tid = threadIdx.x;
  int orig = blockIdx.x;
  int pid = (orig & 7) * 1024 + (orig >> 3);  // XCD swizzle (8192 % 8 == 0)
  int b = pid >> 10;
  int pp = pid & 1023;
  int ph = pp >> 5, pw = pp & 31;

  // stage x patch (4096 floats) cooperatively, coalesced float4
  {
    const float* xb = x + (size_t)b * 64 * HWSZ + (ph * 8) * 256 + pw * 8;
#pragma unroll
    for (int k = 0; k < 4; ++k) {
      int s = tid + k * 256;
      int d = s >> 4, i = (s >> 1) & 7, jh = s & 1;
      float4 v = *(const float4*)(xb + (size_t)d * HWSZ + i * 256 + jh * 4);
      *(float4*)(xs + d * 64 + i * 8 + jh * 4) = v;
    }
  }
  int c = tid;
  float bias = b_in[c];
  float p[64];
#pragma unroll
  for (int t = 0; t < 64; ++t) p[t] = bias;
  __syncthreads();

  // conv_in: p[pix] = bias + sum_d w[c][d] * xs[d][pix]
  // w row per-lane from global (stride 256 B, L2-hot, reused by all blocks)
  const float* wrow = w_in + c * 64;
  for (int d8 = 0; d8 < 8; ++d8) {
    float4 wa = *(const float4*)(wrow + d8 * 8);
    float4 wb = *(const float4*)(wrow + d8 * 8 + 4);
    float wv[8] = {wa.x, wa.y, wa.z, wa.w, wb.x, wb.y, wb.z, wb.w};
#pragma unroll
    for (int dd = 0; dd < 8; ++dd) {
      const float4* xr = (const float4*)(xs + (d8 * 8 + dd) * 64);
#pragma unroll
      for (int t4 = 0; t4 < 16; ++t4) {
        float4 xv = xr[t4];
        p[t4 * 4 + 0] += wv[dd] * xv.x;
        p[t4 * 4 + 1] += wv[dd] * xv.y;
        p[t4 * 4 + 2] += wv[dd] * xv.z;
        p[t4 * 4 + 3] += wv[dd] * xv.w;
      }
    }
  }

  // load per-channel spatial kernel AFTER conv_in (keeps peak VGPR low)
  float kreg[64];
  {
    const float4* kp = (const float4*)(Ks + c * 64);
#pragma unroll
    for (int t4 = 0; t4 < 16; ++t4) {
      float4 kv = kp[t4];
      kreg[t4 * 4 + 0] = kv.x; kreg[t4 * 4 + 1] = kv.y;
      kreg[t4 * 4 + 2] = kv.z; kreg[t4 * 4 + 3] = kv.w;
    }
  }

  // 8x8 circular conv, fully unrolled; pack bf16 pairs; stage in LDS
  uint32_t* srow = su + c * 34;
#pragma unroll
  for (int i = 0; i < 8; ++i) {
    float o[8] = {0.f, 0.f, 0.f, 0.f, 0.f, 0.f, 0.f, 0.f};
#pragma unroll
    for (int tp = 0; tp < 8; ++tp) {
      int r = ((i - tp) & 7) * 8;
#pragma unroll
      for (int tq = 0; tq < 8; ++tq) {
        float kv = kreg[tp * 8 + tq];
#pragma unroll
        for (int j = 0; j < 8; ++j) o[j] += kv * p[r + ((j - tq) & 7)];
      }
    }
    uint2 u0, u1;
    u0.x = f2bfu(o[0]) | (f2bfu(o[1]) << 16);
    u0.y = f2bfu(o[2]) | (f2bfu(o[3]) << 16);
    u1.x = f2bfu(o[4]) | (f2bfu(o[5]) << 16);
    u1.y = f2bfu(o[6]) | (f2bfu(o[7]) << 16);
    *(uint2*)(srow + i * 4) = u0;
    *(uint2*)(srow + i * 4 + 2) = u1;
  }
  __syncthreads();

  // cooperative fully-coalesced write: 8192 uints (32 KB) per block
  uint32_t* gbase = midu + (size_t)(b * 1024 + pp) * 8192;
#pragma unroll
  for (int k = 0; k < 8; ++k) {
    int g = tid * 4 + k * 1024;
    int cc = g >> 5, w = g & 31;
    uint2 a = *(uint2*)(su + cc * 34 + w);
    uint2 e = *(uint2*)(su + cc * 34 + w + 2);
    uint4 q; q.x = a.x; q.y = a.y; q.z = e.x; q.w = e.y;
    *(uint4*)(gbase + g) = q;
  }
}

// ---------------- K2 v3: dw7x7 + bias + GELU + conv_out 1x1 + bias --------
// Block = 32 wide x 16 tall px (1024 blocks). Thread = 2 adjacent px (2tx,
// 2tx+1) in row ty. Tile: bf16-pair uints [22 rows][TU=22], double-buffered.
// dw window read as 3x ds_read_b64/row; all weights via wave-uniform global
// loads (s_load path) -> zero LDS traffic for weights. acc[2][64] in VGPRs.
#define TU 22
__global__ __launch_bounds__(256, 1) void k_back(
    const uint32_t* __restrict__ midu, const float* __restrict__ w_dw,
    const float* __restrict__ b_dw, const float* __restrict__ wT,
    const float* __restrict__ b_out, float* __restrict__ out) {
  __shared__ uint32_t tile[2][22 * TU];  // 3872 B
  int t = threadIdx.x;
  int orig = blockIdx.x;
  int pid = (orig & 7) * 128 + (orig >> 3);  // XCD swizzle (1024 % 8 == 0)
  int b = pid >> 7;
  int tb = pid & 127;
  int th = tb >> 3, tw = tb & 7;  // 16 row-tiles x 8 col-tiles
  int R0 = th * 16, C0 = tw * 32;

  // zero-init both buffers; out-of-image slots stay zero for ALL channels
  for (int z = t; z < 2 * 22 * TU; z += 256) ((uint32_t*)tile)[z] = 0u;

  // loader: t<176: lr = t>>3 (row 0..21), pk = t&7 (patch col 0..5 active)
  int lr = t >> 3, pk = t & 7;
  int g = R0 - 3 + lr;            // global px row
  int pc = 4 * tw - 1 + pk;       // global patch col
  bool ldv = (t < 176) && (pk < 6) && ((unsigned)g < 256u) &&
             ((unsigned)pc < 32u);
  size_t src0 = 0;
  if (ldv)
    src0 = ((size_t)(b * 1024 + (g >> 3) * 32 + pc) * 8192) +
           (size_t)((g & 7) * 4);
  int u0 = 4 * pk - 2;  // lds uint col of quad start (pk=0 -> partial)

  int ty = t >> 4, tx = t & 15;
  int ue = tx & ~1;  // even-floor uint col for b64 window reads
  int o = tx & 1;

  float acc0[64], acc1[64];
#pragma unroll
  for (int d = 0; d < 64; ++d) { acc0[d] = 0.f; acc1[d] = 0.f; }

  __syncthreads();  // zero-init complete before prologue stores (R2 lesson)

  // prologue: stage channel 0 into buffer 0
  if (ldv) {
    uint4 q = *(const uint4*)(midu + src0);
    uint32_t* dr = &tile[0][0] + lr * TU;
    if (pk) {
      uint2 h0; h0.x = q.x; h0.y = q.y;
      uint2 h1; h1.x = q.z; h1.y = q.w;
      *(uint2*)(dr + u0) = h0;
      *(uint2*)(dr + u0 + 2) = h1;
    } else {
      uint2 h1; h1.x = q.z; h1.y = q.w;
      *(uint2*)(dr + 0) = h1;  // only px_rel -4..-1 half lands in-window
    }
  }
  __syncthreads();

  for (int c = 0; c < 256; ++c) {
    int cur = c & 1;
    uint4 q;
    bool pf = (c < 255) && ldv;
    if (pf) q = *(const uint4*)(midu + src0 + (size_t)(c + 1) * 32);

    const uint32_t* tl = &tile[cur][0];
    const float* wr = w_dw + c * 49;  // uniform -> s_load
    float s0 = b_dw[c], s1 = s0;
#pragma unroll
    for (int u = 0; u < 7; ++u) {
      const uint32_t* row = tl + (ty + u) * TU + ue;
      uint2 A = *(const uint2*)(row);
      uint2 B = *(const uint2*)(row + 2);
      uint2 C = *(const uint2*)(row + 4);
      uint32_t sw0 = o ? A.y : A.x;
      uint32_t sw1 = o ? B.x : A.y;
      uint32_t sw2 = o ? B.y : B.x;
      uint32_t sw3 = o ? C.x : B.y;
      uint32_t sw4 = o ? C.y : C.x;
      float f0 = bfhi(sw0), f1 = bflo(sw1), f2 = bfhi(sw1), f3 = bflo(sw2);
      float f4 = bfhi(sw2), f5 = bflo(sw3), f6 = bfhi(sw3), f7 = bflo(sw4);
      float w0 = wr[u * 7 + 0], w1 = wr[u * 7 + 1], w2 = wr[u * 7 + 2];
      float w3 = wr[u * 7 + 3], w4 = wr[u * 7 + 4], w5 = wr[u * 7 + 5];
      float w6 = wr[u * 7 + 6];
      s0 += w0 * f0 + w1 * f1 + w2 * f2 + w3 * f3 + w4 * f4 + w5 * f5 +
            w6 * f6;
      s1 += w0 * f1 + w1 * f2 + w2 * f3 + w3 * f4 + w4 * f5 + w5 * f6 +
            w6 * f7;
    }
    const float RS2 = 0.70710678118654752f;
    float g0 = 0.5f * s0 * (1.f + erff(s0 * RS2));
    float g1 = 0.5f * s1 * (1.f + erff(s1 * RS2));

    const float* wc = wT + c * 64;  // uniform -> s_load
#pragma unroll
    for (int d4 = 0; d4 < 16; ++d4) {
      float4 wv = *(const float4*)(wc + d4 * 4);
      acc0[d4 * 4 + 0] += g0 * wv.x; acc1[d4 * 4 + 0] += g1 * wv.x;
      acc0[d4 * 4 + 1] += g0 * wv.y; acc1[d4 * 4 + 1] += g1 * wv.y;
      acc0[d4 * 4 + 2] += g0 * wv.z; acc1[d4 * 4 + 2] += g1 * wv.z;
      acc0[d4 * 4 + 3] += g0 * wv.w; acc1[d4 * 4 + 3] += g1 * wv.w;
    }

    if (pf) {
      uint32_t* dr = &tile[cur ^ 1][0] + lr * TU;
      if (pk) {
        uint2 h0; h0.x = q.x; h0.y = q.y;
        uint2 h1; h1.x = q.z; h1.y = q.w;
        *(uint2*)(dr + u0) = h0;
        *(uint2*)(dr + u0 + 2) = h1;
      } else {
        uint2 h1; h1.x = q.z; h1.y = q.w;
        *(uint2*)(dr + 0) = h1;
      }
    }
    __syncthreads();
  }

  // coalesced float2 stores: lanes cover consecutive 8B spans of each row
  size_t obase = (size_t)b * 64 * HWSZ + (size_t)(R0 + ty) * 256 + C0 + 2 * tx;
#pragma unroll
  for (int d = 0; d < 64; ++d) {
    float bo = b_out[d];  // uniform -> s_load
    float2 v; v.x = acc0[d] + bo; v.y = acc1[d] + bo;
    *(float2*)(out + obase + (size_t)d * HWSZ) = v;
  }
}

extern "C" void kernel_launch(void* const* d_in, const int* in_sizes, int n_in,
                              void* d_out, int out_size, void* d_ws, size_t ws_size,
                              hipStream_t stream) {
  (void)in_sizes; (void)n_in; (void)out_size; (void)ws_size;
  const float* x     = (const float*)d_in[0];
  const float* w_in  = (const float*)d_in[1];
  const float* b_in  = (const float*)d_in[2];
  const float* fftf  = (const float*)d_in[3];
  const float* w_dw  = (const float*)d_in[4];
  const float* b_dw  = (const float*)d_in[5];
  const float* w_out = (const float*)d_in[6];
  const float* b_out = (const float*)d_in[7];
  float* out = (float*)d_out;

  float* Ks = (float*)d_ws;                                   // 64 KB
  float* wT = (float*)((char*)d_ws + 65536);                  // 64 KB
  uint32_t* midu = (uint32_t*)((char*)d_ws + 131072);         // 268 MB

  k_prep<<<256, 64, 0, stream>>>(fftf, Ks);
  k_wt<<<256, 64, 0, stream>>>(w_out, wT);
  k_front<<<8192, 256, 0, stream>>>(x, w_in, b_in, Ks, midu);
  k_back<<<1024, 256, 0, stream>>>(midu, w_dw, b_dw, wT, b_out, out);
}

// Round 3
// 1956.684 us; speedup vs baseline: 2.4383x; 1.7041x over previous
//
#include <hip/hip_runtime.h>
#include <cstdint>
#include <cstddef>

#define HWSZ 65536  // 256*256

__device__ __forceinline__ uint32_t f2bfu(float f) {
  union { float f; uint32_t u; } v; v.f = f;
  return (v.u + 0x7FFFu + ((v.u >> 16) & 1u)) >> 16;  // RNE bf16, as uint
}
__device__ __forceinline__ float bfu2f(uint32_t s) {
  union { uint32_t u; float f; } v; v.u = s << 16;
  return v.f;
}
__device__ __forceinline__ float bfhi(uint32_t u) {  // high bf16 of pair
  union { uint32_t u; float f; } v; v.u = u & 0xffff0000u;
  return v.f;
}
__device__ __forceinline__ float bflo(uint32_t u) {  // low bf16 of pair
  union { uint32_t u; float f; } v; v.u = u << 16;
  return v.f;
}

// ---------------- K0: spatial kernel from rfft2 filter --------------------
__global__ void k_prep(const float* __restrict__ F, float* __restrict__ Ks) {
  __shared__ float ct[8];
  int t = threadIdx.x;
  int c = blockIdx.x;
  if (t == 0) {
    const float r2 = 0.70710678118654752f;
    ct[0] = 1.f; ct[1] = r2; ct[2] = 0.f; ct[3] = -r2;
    ct[4] = -1.f; ct[5] = -r2; ct[6] = 0.f; ct[7] = r2;
  }
  __syncthreads();
  int p = t >> 3, q = t & 7;
  const float* Fc = F + c * 40;
  float s = 0.f;
#pragma unroll
  for (int u = 0; u < 8; ++u) {
#pragma unroll
    for (int v = 0; v < 8; ++v) {
      float g = (v <= 4) ? Fc[u * 5 + v] : Fc[((8 - u) & 7) * 5 + (8 - v)];
      s += g * ct[(u * p + v * q) & 7];
    }
  }
  Ks[c * 64 + t] = s * (1.f / 64.f);
}

// ---------------- K0b: transpose w_out [64][256] -> wT [256][64] ----------
__global__ void k_wt(const float* __restrict__ w_out, float* __restrict__ wT) {
  int c = blockIdx.x;   // 256
  int d = threadIdx.x;  // 64
  wT[c * 64 + d] = w_out[d * 256 + c];
}

// ---------------- K1: conv_in 1x1 + bias + patch circular conv ------------
// one 8x8 patch per block, thread = channel c (0..255)
// v4: same structure as v3 (xs in LDS, w_in per-lane global, su bf16 staging)
// but __launch_bounds__(256,2): real register demand is ~180 VGPR
// (p[64]+kreg[64]+addressing; proven no-spill at cap 256 in R0, proven
// SPILL-CASCADE at cap 168 in R1/R2 -> VGPR_Count 84, 9 GB scratch traffic).
// 2 blocks/CU: VGPR 180 -> 2 waves/SIMD; LDS 51200*2 = 102.4 KB <= 160 KB.
// mid layout (uint32 = 2 bf16 pixels): [b][patch][c][pix/2] -> block-contig 32KB
__global__ __launch_bounds__(256, 2) void k_front(
    const float* __restrict__ x, const float* __restrict__ w_in,
    const float* __restrict__ b_in, const float* __restrict__ Ks,
    uint32_t* __restrict__ midu) {
  __shared__ float xs[64 * 64];      // 16 KB [d][pix]
  __shared__ uint32_t su[256 * 34];  // 34816 B bf16-pair staging
  int tid = threadIdx.x;
  int orig = blockIdx.x;
  int pid = (orig & 7) * 1024 + (orig >> 3);  // XCD swizzle (8192 % 8 == 0)
  int b = pid >> 10;
  int pp = pid & 1023;
  int ph = pp >> 5, pw = pp & 31;

  // stage x patch (4096 floats) cooperatively, coalesced float4
  {
    const float* xb = x + (size_t)b * 64 * HWSZ + (ph * 8) * 256 + pw * 8;
#pragma unroll
    for (int k = 0; k < 4; ++k) {
      int s = tid + k * 256;
      int d = s >> 4, i = (s >> 1) & 7, jh = s & 1;
      float4 v = *(const float4*)(xb + (size_t)d * HWSZ + i * 256 + jh * 4);
      *(float4*)(xs + d * 64 + i * 8 + jh * 4) = v;
    }
  }
  int c = tid;
  float bias = b_in[c];
  float p[64];
#pragma unroll
  for (int t = 0; t < 64; ++t) p[t] = bias;
  __syncthreads();

  // conv_in: p[pix] = bias + sum_d w[c][d] * xs[d][pix]
  // w row per-lane from global (stride 256 B, L2-hot, reused by all blocks)
  const float* wrow = w_in + c * 64;
  for (int d8 = 0; d8 < 8; ++d8) {
    float4 wa = *(const float4*)(wrow + d8 * 8);
    float4 wb = *(const float4*)(wrow + d8 * 8 + 4);
    float wv[8] = {wa.x, wa.y, wa.z, wa.w, wb.x, wb.y, wb.z, wb.w};
#pragma unroll
    for (int dd = 0; dd < 8; ++dd) {
      const float4* xr = (const float4*)(xs + (d8 * 8 + dd) * 64);
#pragma unroll
      for (int t4 = 0; t4 < 16; ++t4) {
        float4 xv = xr[t4];
        p[t4 * 4 + 0] += wv[dd] * xv.x;
        p[t4 * 4 + 1] += wv[dd] * xv.y;
        p[t4 * 4 + 2] += wv[dd] * xv.z;
        p[t4 * 4 + 3] += wv[dd] * xv.w;
      }
    }
  }

  // load per-channel spatial kernel AFTER conv_in (keeps peak VGPR low)
  float kreg[64];
  {
    const float4* kp = (const float4*)(Ks + c * 64);
#pragma unroll
    for (int t4 = 0; t4 < 16; ++t4) {
      float4 kv = kp[t4];
      kreg[t4 * 4 + 0] = kv.x; kreg[t4 * 4 + 1] = kv.y;
      kreg[t4 * 4 + 2] = kv.z; kreg[t4 * 4 + 3] = kv.w;
    }
  }

  // 8x8 circular conv, fully unrolled; pack bf16 pairs; stage in LDS
  uint32_t* srow = su + c * 34;
#pragma unroll
  for (int i = 0; i < 8; ++i) {
    float o[8] = {0.f, 0.f, 0.f, 0.f, 0.f, 0.f, 0.f, 0.f};
#pragma unroll
    for (int tp = 0; tp < 8; ++tp) {
      int r = ((i - tp) & 7) * 8;
#pragma unroll
      for (int tq = 0; tq < 8; ++tq) {
        float kv = kreg[tp * 8 + tq];
#pragma unroll
        for (int j = 0; j < 8; ++j) o[j] += kv * p[r + ((j - tq) & 7)];
      }
    }
    uint2 u0, u1;
    u0.x = f2bfu(o[0]) | (f2bfu(o[1]) << 16);
    u0.y = f2bfu(o[2]) | (f2bfu(o[3]) << 16);
    u1.x = f2bfu(o[4]) | (f2bfu(o[5]) << 16);
    u1.y = f2bfu(o[6]) | (f2bfu(o[7]) << 16);
    *(uint2*)(srow + i * 4) = u0;
    *(uint2*)(srow + i * 4 + 2) = u1;
  }
  __syncthreads();

  // cooperative fully-coalesced write: 8192 uints (32 KB) per block
  uint32_t* gbase = midu + (size_t)(b * 1024 + pp) * 8192;
#pragma unroll
  for (int k = 0; k < 8; ++k) {
    int g = tid * 4 + k * 1024;
    int cc = g >> 5, w = g & 31;
    uint2 a = *(uint2*)(su + cc * 34 + w);
    uint2 e = *(uint2*)(su + cc * 34 + w + 2);
    uint4 q; q.x = a.x; q.y = a.y; q.z = e.x; q.w = e.y;
    *(uint4*)(gbase + g) = q;
  }
}

// ---------------- K2 v3: dw7x7 + bias + GELU + conv_out 1x1 + bias --------
// Block = 32 wide x 16 tall px (1024 blocks). Thread = 2 adjacent px (2tx,
// 2tx+1) in row ty. Tile: bf16-pair uints [22 rows][TU=22], double-buffered.
// dw window read as 3x ds_read_b64/row; all weights via wave-uniform global
// loads (s_load path) -> zero LDS traffic for weights. acc[2][64] in VGPRs.
#define TU 22
__global__ __launch_bounds__(256, 1) void k_back(
    const uint32_t* __restrict__ midu, const float* __restrict__ w_dw,
    const float* __restrict__ b_dw, const float* __restrict__ wT,
    const float* __restrict__ b_out, float* __restrict__ out) {
  __shared__ uint32_t tile[2][22 * TU];  // 3872 B
  int t = threadIdx.x;
  int orig = blockIdx.x;
  int pid = (orig & 7) * 128 + (orig >> 3);  // XCD swizzle (1024 % 8 == 0)
  int b = pid >> 7;
  int tb = pid & 127;
  int th = tb >> 3, tw = tb & 7;  // 16 row-tiles x 8 col-tiles
  int R0 = th * 16, C0 = tw * 32;

  // zero-init both buffers; out-of-image slots stay zero for ALL channels
  for (int z = t; z < 2 * 22 * TU; z += 256) ((uint32_t*)tile)[z] = 0u;

  // loader: t<176: lr = t>>3 (row 0..21), pk = t&7 (patch col 0..5 active)
  int lr = t >> 3, pk = t & 7;
  int g = R0 - 3 + lr;            // global px row
  int pc = 4 * tw - 1 + pk;       // global patch col
  bool ldv = (t < 176) && (pk < 6) && ((unsigned)g < 256u) &&
             ((unsigned)pc < 32u);
  size_t src0 = 0;
  if (ldv)
    src0 = ((size_t)(b * 1024 + (g >> 3) * 32 + pc) * 8192) +
           (size_t)((g & 7) * 4);
  int u0 = 4 * pk - 2;  // lds uint col of quad start (pk=0 -> partial)

  int ty = t >> 4, tx = t & 15;
  int ue = tx & ~1;  // even-floor uint col for b64 window reads
  int o = tx & 1;

  float acc0[64], acc1[64];
#pragma unroll
  for (int d = 0; d < 64; ++d) { acc0[d] = 0.f; acc1[d] = 0.f; }

  __syncthreads();  // zero-init complete before prologue stores (R2 lesson)

  // prologue: stage channel 0 into buffer 0
  if (ldv) {
    uint4 q = *(const uint4*)(midu + src0);
    uint32_t* dr = &tile[0][0] + lr * TU;
    if (pk) {
      uint2 h0; h0.x = q.x; h0.y = q.y;
      uint2 h1; h1.x = q.z; h1.y = q.w;
      *(uint2*)(dr + u0) = h0;
      *(uint2*)(dr + u0 + 2) = h1;
    } else {
      uint2 h1; h1.x = q.z; h1.y = q.w;
      *(uint2*)(dr + 0) = h1;  // only px_rel -4..-1 half lands in-window
    }
  }
  __syncthreads();

  for (int c = 0; c < 256; ++c) {
    int cur = c & 1;
    uint4 q;
    bool pf = (c < 255) && ldv;
    if (pf) q = *(const uint4*)(midu + src0 + (size_t)(c + 1) * 32);

    const uint32_t* tl = &tile[cur][0];
    const float* wr = w_dw + c * 49;  // uniform -> s_load
    float s0 = b_dw[c], s1 = s0;
#pragma unroll
    for (int u = 0; u < 7; ++u) {
      const uint32_t* row = tl + (ty + u) * TU + ue;
      uint2 A = *(const uint2*)(row);
      uint2 B = *(const uint2*)(row + 2);
      uint2 C = *(const uint2*)(row + 4);
      uint32_t sw0 = o ? A.y : A.x;
      uint32_t sw1 = o ? B.x : A.y;
      uint32_t sw2 = o ? B.y : B.x;
      uint32_t sw3 = o ? C.x : B.y;
      uint32_t sw4 = o ? C.y : C.x;
      float f0 = bfhi(sw0), f1 = bflo(sw1), f2 = bfhi(sw1), f3 = bflo(sw2);
      float f4 = bfhi(sw2), f5 = bflo(sw3), f6 = bfhi(sw3), f7 = bflo(sw4);
      float w0 = wr[u * 7 + 0], w1 = wr[u * 7 + 1], w2 = wr[u * 7 + 2];
      float w3 = wr[u * 7 + 3], w4 = wr[u * 7 + 4], w5 = wr[u * 7 + 5];
      float w6 = wr[u * 7 + 6];
      s0 += w0 * f0 + w1 * f1 + w2 * f2 + w3 * f3 + w4 * f4 + w5 * f5 +
            w6 * f6;
      s1 += w0 * f1 + w1 * f2 + w2 * f3 + w3 * f4 + w4 * f5 + w5 * f6 +
            w6 * f7;
    }
    const float RS2 = 0.70710678118654752f;
    float g0 = 0.5f * s0 * (1.f + erff(s0 * RS2));
    float g1 = 0.5f * s1 * (1.f + erff(s1 * RS2));

    const float* wc = wT + c * 64;  // uniform -> s_load
#pragma unroll
    for (int d4 = 0; d4 < 16; ++d4) {
      float4 wv = *(const float4*)(wc + d4 * 4);
      acc0[d4 * 4 + 0] += g0 * wv.x; acc1[d4 * 4 + 0] += g1 * wv.x;
      acc0[d4 * 4 + 1] += g0 * wv.y; acc1[d4 * 4 + 1] += g1 * wv.y;
      acc0[d4 * 4 + 2] += g0 * wv.z; acc1[d4 * 4 + 2] += g1 * wv.z;
      acc0[d4 * 4 + 3] += g0 * wv.w; acc1[d4 * 4 + 3] += g1 * wv.w;
    }

    if (pf) {
      uint32_t* dr = &tile[cur ^ 1][0] + lr * TU;
      if (pk) {
        uint2 h0; h0.x = q.x; h0.y = q.y;
        uint2 h1; h1.x = q.z; h1.y = q.w;
        *(uint2*)(dr + u0) = h0;
        *(uint2*)(dr + u0 + 2) = h1;
      } else {
        uint2 h1; h1.x = q.z; h1.y = q.w;
        *(uint2*)(dr + 0) = h1;
      }
    }
    __syncthreads();
  }

  // coalesced float2 stores: lanes cover consecutive 8B spans of each row
  size_t obase = (size_t)b * 64 * HWSZ + (size_t)(R0 + ty) * 256 + C0 + 2 * tx;
#pragma unroll
  for (int d = 0; d < 64; ++d) {
    float bo = b_out[d];  // uniform -> s_load
    float2 v; v.x = acc0[d] + bo; v.y = acc1[d] + bo;
    *(float2*)(out + obase + (size_t)d * HWSZ) = v;
  }
}

extern "C" void kernel_launch(void* const* d_in, const int* in_sizes, int n_in,
                              void* d_out, int out_size, void* d_ws, size_t ws_size,
                              hipStream_t stream) {
  (void)in_sizes; (void)n_in; (void)out_size; (void)ws_size;
  const float* x     = (const float*)d_in[0];
  const float* w_in  = (const float*)d_in[1];
  const float* b_in  = (const float*)d_in[2];
  const float* fftf  = (const float*)d_in[3];
  const float* w_dw  = (const float*)d_in[4];
  const float* b_dw  = (const float*)d_in[5];
  const float* w_out = (const float*)d_in[6];
  const float* b_out = (const float*)d_in[7];
  float* out = (float*)d_out;

  float* Ks = (float*)d_ws;                                   // 64 KB
  float* wT = (float*)((char*)d_ws + 65536);                  // 64 KB
  uint32_t* midu = (uint32_t*)((char*)d_ws + 131072);         // 268 MB

  k_prep<<<256, 64, 0, stream>>>(fftf, Ks);
  k_wt<<<256, 64, 0, stream>>>(w_out, wT);
  k_front<<<8192, 256, 0, stream>>>(x, w_in, b_in, Ks, midu);
  k_back<<<1024, 256, 0, stream>>>(midu, w_dw, b_dw, wT, b_out, out);
}